// Round 12
// baseline (3272.412 us; speedup 1.0000x reference)
//
#include <hip/hip_runtime.h>
#include <hip/hip_bf16.h>
#include <hip/hip_cooperative_groups.h>
#include <cmath>

namespace cg = cooperative_groups;

#define NROW 2048      // B*S
#define DMODEL 512
#define FIN 240
#define FINPAD 256
#define NHEAD 16
#define DHEAD 32
#define CHUNK 64
#define NCHUNK 16      // S / CHUNK
#define NLAYER 6
#define SEQ 1024
#define QKVLD 1536
#define GRID 512
#define BLOCK 256

typedef __attribute__((ext_vector_type(8))) short bf16x8;
typedef __attribute__((ext_vector_type(4))) float f32x4;
typedef __attribute__((ext_vector_type(4))) unsigned short u16x4;

#define MFMA_BF16 __builtin_amdgcn_mfma_f32_16x16x32_bf16

// phi(x) = elu(x) + 1
__device__ __forceinline__ float phi(float x) {
    return x > 0.f ? x + 1.f : expf(x);
}

__device__ __forceinline__ float bf2f(unsigned short u) {
    return __uint_as_float((unsigned)u << 16);
}

__device__ __forceinline__ unsigned short f2bf_bits(float z) {
    __hip_bfloat16 hb_ = __float2bfloat16(z);
    return *reinterpret_cast<unsigned short*>(&hb_);
}

__device__ __forceinline__ void load_lds16(const void* g, void* l) {
    __builtin_amdgcn_global_load_lds(
        (const __attribute__((address_space(1))) void*)g,
        (__attribute__((address_space(3))) void*)l, 16, 0, 0);
}

// ---------------- LN phase: 1 wave/row, 4 rows/block (grid must be 512) ----
__device__ __forceinline__ void ln_phase(
    const float* __restrict__ in,
    const float* __restrict__ g, const float* __restrict__ b,
    float* __restrict__ out, __hip_bfloat16* __restrict__ outb,
    int C, int Cpad) {
    int wv = threadIdx.x >> 6, t = threadIdx.x & 63;
    int row = blockIdx.x * 4 + wv;
    const float* xr = in + (size_t)row * C;
    f32x4 v[2] = {{0.f,0.f,0.f,0.f},{0.f,0.f,0.f,0.f}};
    float sum = 0.f, sq = 0.f;
#pragma unroll
    for (int i = 0; i < 2; ++i) {
        int c = (t + i * 64) * 4;
        if (c < C) {
            f32x4 x_ = *(const f32x4*)&xr[c];
            v[i] = x_;
#pragma unroll
            for (int j = 0; j < 4; ++j) { sum += x_[j]; sq += x_[j] * x_[j]; }
        }
    }
#pragma unroll
    for (int off = 32; off > 0; off >>= 1) {
        sum += __shfl_xor(sum, off, 64);
        sq  += __shfl_xor(sq,  off, 64);
    }
    float mean = sum / (float)C;
    float var  = sq / (float)C - mean * mean;
    float rstd = rsqrtf(var + 1e-5f);
#pragma unroll
    for (int i = 0; i < 2; ++i) {
        int c = (t + i * 64) * 4;
        f32x4 y;
#pragma unroll
        for (int j = 0; j < 4; ++j) y[j] = (v[i][j] - mean) * rstd;
        if (c < C) {
            f32x4 gg = *(const f32x4*)&g[c];
            f32x4 bb = *(const f32x4*)&b[c];
#pragma unroll
            for (int j = 0; j < 4; ++j) y[j] = y[j] * gg[j] + bb[j];
            if (out) *(f32x4*)&out[(size_t)row * C + c] = y;
        }
        if (outb && c < Cpad) {
            u16x4 o;
#pragma unroll
            for (int j = 0; j < 4; ++j) {
                float z = (c + j < C) ? y[j] : 0.f;
                o[j] = f2bf_bits(z);
            }
            *(u16x4*)&outb[(size_t)row * Cpad + c] = o;
        }
    }
}

// ---------------- GEMM phase: 64x64 tile, ring-4 counted-vmcnt, grid-stride -
// C = A[2048,K] * Bt[N,K]^T + bias (+ optional residual). smem = 64 KB arena.
template<int RELU, int WF32, int WBF16, int PHI, int RES, int K>
__device__ __forceinline__ void gemm_phase(char* smem,
    const __hip_bfloat16* __restrict__ A, const __hip_bfloat16* __restrict__ Bt,
    const float* __restrict__ bias,
    float* __restrict__ C, __hip_bfloat16* __restrict__ Cb,
    const float* __restrict__ Rres, int N) {
    constexpr int NSTEP = K / 64;
    auto As = reinterpret_cast<__hip_bfloat16 (*)[64][64]>(smem);
    auto Bs = reinterpret_cast<__hip_bfloat16 (*)[64][64]>(smem + 32768);
    const int tid = threadIdx.x, lane = tid & 63, w = tid >> 6;
    const int nN = N >> 6;
    const int T = 32 * nN;                        // M = 2048 fixed
    const int srow  = lane >> 3;                  // 0..7
    const int sslot = (lane & 7) ^ srow;          // pre-swizzled global slot
    const size_t aoff = (size_t)srow * K + (size_t)sslot * 8;
    const int wm = (w >> 1) << 5, wn = (w & 1) << 5;
    const int fr = lane & 15, fq = lane >> 4;
    const int sw = fr & 7;
    const int e0 = ((fq      ^ sw) << 3);
    const int e1 = (((fq | 4) ^ sw) << 3);

    for (int tile = blockIdx.x; tile < T; tile += gridDim.x) {
        const int bm = (tile / nN) * 64;
        const int bn = (tile % nN) * 64;
        const __hip_bfloat16* gA0 = A  + (size_t)(bm + w * 8) * K + aoff;
        const __hip_bfloat16* gA1 = A  + (size_t)(bm + 32 + w * 8) * K + aoff;
        const __hip_bfloat16* gB0 = Bt + (size_t)(bn + w * 8) * K + aoff;
        const __hip_bfloat16* gB1 = Bt + (size_t)(bn + 32 + w * 8) * K + aoff;
        __syncthreads();   // prior LDS readers done before re-staging

#define STAGE(t) do { \
        load_lds16(gA0 + (size_t)(t) * 64, &As[(t) & 3][w * 8][0]); \
        load_lds16(gA1 + (size_t)(t) * 64, &As[(t) & 3][32 + w * 8][0]); \
        load_lds16(gB0 + (size_t)(t) * 64, &Bs[(t) & 3][w * 8][0]); \
        load_lds16(gB1 + (size_t)(t) * 64, &Bs[(t) & 3][32 + w * 8][0]); \
    } while (0)

        f32x4 acc00 = {0.f, 0.f, 0.f, 0.f}, acc01 = acc00, acc10 = acc00, acc11 = acc00;
        STAGE(0); STAGE(1); STAGE(2);
#pragma unroll
        for (int t = 0; t < NSTEP; ++t) {
            if (NSTEP - t >= 3)      asm volatile("s_waitcnt vmcnt(8)" ::: "memory");
            else if (NSTEP - t == 2) asm volatile("s_waitcnt vmcnt(4)" ::: "memory");
            else                     asm volatile("s_waitcnt vmcnt(0)" ::: "memory");
            __builtin_amdgcn_s_barrier();
            __builtin_amdgcn_sched_barrier(0);
            if (t + 3 < NSTEP) STAGE(t + 3);
            const int b = t & 3;
            bf16x8 a00 = *(const bf16x8*)&As[b][wm + fr][e0];
            bf16x8 a01 = *(const bf16x8*)&As[b][wm + fr][e1];
            bf16x8 a10 = *(const bf16x8*)&As[b][wm + 16 + fr][e0];
            bf16x8 a11 = *(const bf16x8*)&As[b][wm + 16 + fr][e1];
            bf16x8 b00 = *(const bf16x8*)&Bs[b][wn + fr][e0];
            bf16x8 b01 = *(const bf16x8*)&Bs[b][wn + fr][e1];
            bf16x8 b10 = *(const bf16x8*)&Bs[b][wn + 16 + fr][e0];
            bf16x8 b11 = *(const bf16x8*)&Bs[b][wn + 16 + fr][e1];
            acc00 = MFMA_BF16(a00, b00, acc00, 0, 0, 0);
            acc01 = MFMA_BF16(a00, b10, acc01, 0, 0, 0);
            acc10 = MFMA_BF16(a10, b00, acc10, 0, 0, 0);
            acc11 = MFMA_BF16(a10, b10, acc11, 0, 0, 0);
            acc00 = MFMA_BF16(a01, b01, acc00, 0, 0, 0);
            acc01 = MFMA_BF16(a01, b11, acc01, 0, 0, 0);
            acc10 = MFMA_BF16(a11, b01, acc10, 0, 0, 0);
            acc11 = MFMA_BF16(a11, b11, acc11, 0, 0, 0);
        }
#undef STAGE

        const int orow = bm + wm + (fq << 2);
        const int ocol = bn + wn + fr;
        float bv0 = bias[ocol], bv1 = bias[ocol + 16];
        f32x4 accs[2][2] = {{acc00, acc01}, {acc10, acc11}};
#pragma unroll
        for (int i = 0; i < 2; ++i)
#pragma unroll
            for (int r = 0; r < 4; ++r) {
                int row = orow + i * 16 + r;
                float v0 = accs[i][0][r] + bv0;
                float v1 = accs[i][1][r] + bv1;
                if (RES) {
                    v0 += Rres[(size_t)row * N + ocol];
                    v1 += Rres[(size_t)row * N + ocol + 16];
                }
                if (RELU) { v0 = fmaxf(v0, 0.f); v1 = fmaxf(v1, 0.f); }
                if (PHI) {
                    if (ocol < 1024)      v0 = phi(v0);
                    if (ocol + 16 < 1024) v1 = phi(v1);
                }
                if (WF32) {
                    C[(size_t)row * N + ocol]      = v0;
                    C[(size_t)row * N + ocol + 16] = v1;
                }
                if (WBF16) {
                    Cb[(size_t)row * N + ocol]      = __float2bfloat16(v0);
                    Cb[(size_t)row * N + ocol + 16] = __float2bfloat16(v1);
                }
            }
    }
}

// ---------------- attn phase A: S_c = V^T K (32x32, bf16) + K col sums -----
// exactly 512 blocks; wave w computes output quadrant (wr, wc)
__device__ __forceinline__ void attnA_phase(char* smem,
    const __hip_bfloat16* __restrict__ qkvb,
    __hip_bfloat16* __restrict__ Sg, float* __restrict__ ksumg) {
    auto Kt = reinterpret_cast<__hip_bfloat16 (*)[72]>(smem);          // [32][72]
    auto Vt = reinterpret_cast<__hip_bfloat16 (*)[72]>(smem + 4608);   // [32][72]
    int bid = blockIdx.x;
    int c = bid & 15, hh = (bid >> 4) & 15, b = bid >> 8;
    int tid = threadIdx.x;
    int row = tid >> 2, slot = tid & 3;
    size_t rb = ((size_t)(b * SEQ + c * CHUNK)) * QKVLD + hh * DHEAD;
    bf16x8 kv = *(const bf16x8*)&qkvb[rb + (size_t)row * QKVLD + 512 + slot * 8];
    bf16x8 vv = *(const bf16x8*)&qkvb[rb + (size_t)row * QKVLD + 1024 + slot * 8];
#pragma unroll
    for (int i = 0; i < 8; ++i) {
        Kt[slot * 8 + i][row] = ((const __hip_bfloat16*)&kv)[i];
        Vt[slot * 8 + i][row] = ((const __hip_bfloat16*)&vv)[i];
    }
    __syncthreads();
    int lane = tid & 63, w = tid >> 6;
    int fr = lane & 15, fq = lane >> 4;
    int wr = w >> 1, wc = w & 1;
    f32x4 acc = {0.f, 0.f, 0.f, 0.f};
#pragma unroll
    for (int ks = 0; ks < 2; ++ks) {
        bf16x8 v_ = *(const bf16x8*)&Vt[wr * 16 + fr][ks * 32 + fq * 8];
        bf16x8 k_ = *(const bf16x8*)&Kt[wc * 16 + fr][ks * 32 + fq * 8];
        acc = MFMA_BF16(v_, k_, acc, 0, 0, 0);
    }
    size_t cb = (size_t)((b * NHEAD + hh) * NCHUNK + c);
    size_t ob = cb * 1024;
#pragma unroll
    for (int r = 0; r < 4; ++r)
        Sg[ob + (size_t)(wr * 16 + fq * 4 + r) * 32 + wc * 16 + fr] =
            __float2bfloat16(acc[r]);
    // K column sums: dim d handled by an 8-thread group
    int d = tid >> 3, s0 = (tid & 7) * 8;
    float part = 0.f;
#pragma unroll
    for (int i = 0; i < 8; ++i) part += __bfloat162float(Kt[d][s0 + i]);
    part += __shfl_xor(part, 1, 64);
    part += __shfl_xor(part, 2, 64);
    part += __shfl_xor(part, 4, 64);
    if ((tid & 7) == 0) ksumg[cb * 32 + d] = part;
}

// ---------------- attn phase B: intra-chunk + state + output (512 blocks) ---
__device__ __forceinline__ void attnB_phase(char* smem,
    const __hip_bfloat16* __restrict__ qkvb,
    const __hip_bfloat16* __restrict__ Sg, const float* __restrict__ ksumg,
    __hip_bfloat16* __restrict__ out) {
    auto Qs  = reinterpret_cast<__hip_bfloat16 (*)[40]>(smem);           // [64][40]
    auto Ks  = reinterpret_cast<__hip_bfloat16 (*)[40]>(smem + 5120);    // [64][40]
    auto Vt  = reinterpret_cast<__hip_bfloat16 (*)[72]>(smem + 10240);   // [32][72]
    auto Awb = reinterpret_cast<__hip_bfloat16 (*)[72]>(smem + 14848);   // [64][72]
    auto Stb = reinterpret_cast<__hip_bfloat16 (*)[40]>(smem + 24064);   // [32][40]
    float* den  = reinterpret_cast<float*>(smem + 26624);                // [64]
    float* ksml = reinterpret_cast<float*>(smem + 26880);                // [32]
    int bid = blockIdx.x;
    int c = bid & 15, hh = (bid >> 4) & 15, b = bid >> 8;
    int tid = threadIdx.x, lane = tid & 63, w = tid >> 6;
    size_t rb = ((size_t)(b * SEQ + c * CHUNK)) * QKVLD + hh * DHEAD;
    {
        int row = tid >> 2, slot = tid & 3;
        *(bf16x8*)&Qs[row][slot * 8] =
            *(const bf16x8*)&qkvb[rb + (size_t)row * QKVLD + slot * 8];
        *(bf16x8*)&Ks[row][slot * 8] =
            *(const bf16x8*)&qkvb[rb + (size_t)row * QKVLD + 512 + slot * 8];
        bf16x8 vv = *(const bf16x8*)&qkvb[rb + (size_t)row * QKVLD + 1024 + slot * 8];
#pragma unroll
        for (int i = 0; i < 8; ++i)
            Vt[slot * 8 + i][row] = ((const __hip_bfloat16*)&vv)[i];
    }
    // state prefix (bf16 chunks, fp32 accumulate)
    size_t sb = ((size_t)((b * NHEAD + hh) * NCHUNK)) * 1024;
    {
        f32x4 st = {0.f, 0.f, 0.f, 0.f};
        for (int cp = 0; cp < c; ++cp) {
            u16x4 sv = *(const u16x4*)&Sg[sb + (size_t)cp * 1024 + tid * 4];
#pragma unroll
            for (int i = 0; i < 4; ++i) st[i] += bf2f(sv[i]);
        }
        int m = tid >> 3, d0 = (tid & 7) * 4;
#pragma unroll
        for (int i = 0; i < 4; ++i) Stb[m][d0 + i] = __float2bfloat16(st[i]);
    }
    if (tid < 32) {
        size_t kb = ((size_t)((b * NHEAD + hh) * NCHUNK)) * 32;
        float s_ = 0.f;
        for (int cp = 0; cp < c; ++cp) s_ += ksumg[kb + cp * 32 + tid];
        ksml[tid] = s_;
    }
    __syncthreads();
    int fr = lane & 15, fq = lane >> 4;
    bf16x8 aQ = *(const bf16x8*)&Qs[w * 16 + fr][fq * 8];
    f32x4 p[4];
#pragma unroll
    for (int j = 0; j < 4; ++j) {
        f32x4 z = {0.f, 0.f, 0.f, 0.f};
        bf16x8 bK = *(const bf16x8*)&Ks[j * 16 + fr][fq * 8];
        p[j] = MFMA_BF16(aQ, bK, z, 0, 0, 0);
    }
    float rs[4] = {0.f, 0.f, 0.f, 0.f};
#pragma unroll
    for (int j = 0; j < 4; ++j) {
        int tcol = j * 16 + fr;
#pragma unroll
        for (int r = 0; r < 4; ++r) {
            int s = w * 16 + fq * 4 + r;
            float val = (tcol <= s) ? p[j][r] : 0.f;
            p[j][r] = val;
            rs[r] += val;
        }
    }
#pragma unroll
    for (int off = 8; off > 0; off >>= 1) {
#pragma unroll
        for (int r = 0; r < 4; ++r) rs[r] += __shfl_xor(rs[r], off, 64);
    }
    if (fr == 0) {
#pragma unroll
        for (int r = 0; r < 4; ++r) den[w * 16 + fq * 4 + r] = rs[r];
    }
#pragma unroll
    for (int j = 0; j < 4; ++j)
#pragma unroll
        for (int r = 0; r < 4; ++r)
            Awb[w * 16 + fq * 4 + r][j * 16 + fr] = __float2bfloat16(p[j][r]);
    __syncthreads();
    if (tid < 64) {
        float dq = den[tid];
        float dst_ = 0.f;
#pragma unroll
        for (int d = 0; d < 32; ++d)
            dst_ += __bfloat162float(Qs[tid][d]) * ksml[d];
        den[tid] = 1.f / (dq + dst_ + 1e-6f);
    }
    __syncthreads();
    size_t orb = ((size_t)(b * SEQ + c * CHUNK)) * DMODEL + hh * DHEAD;
#pragma unroll
    for (int mf = 0; mf < 2; ++mf) {
        f32x4 acc = {0.f, 0.f, 0.f, 0.f};
        bf16x8 bS = *(const bf16x8*)&Stb[mf * 16 + fr][fq * 8];
        acc = MFMA_BF16(aQ, bS, acc, 0, 0, 0);
#pragma unroll
        for (int ks = 0; ks < 2; ++ks) {
            bf16x8 aA = *(const bf16x8*)&Awb[w * 16 + fr][ks * 32 + fq * 8];
            bf16x8 bV = *(const bf16x8*)&Vt[mf * 16 + fr][ks * 32 + fq * 8];
            acc = MFMA_BF16(aA, bV, acc, 0, 0, 0);
        }
#pragma unroll
        for (int r = 0; r < 4; ++r) {
            int s = w * 16 + fq * 4 + r;
            out[orb + (size_t)s * DMODEL + mf * 16 + fr] =
                __float2bfloat16(acc[r] * den[s]);
        }
    }
}

// ---------------- weight transpose + bf16 convert (+ qkv bias concat) -------
__global__ __launch_bounds__(256) void wconv_kernel(
    const float* __restrict__ W_pre, const float* __restrict__ Wq,
    const float* __restrict__ Wk, const float* __restrict__ Wv,
    const float* __restrict__ Wo, const float* __restrict__ W1,
    const float* __restrict__ W2, const float* __restrict__ W_post,
    const float* __restrict__ bq, const float* __restrict__ bk,
    const float* __restrict__ bv, float* __restrict__ qkvbias,
    __hip_bfloat16* wpre_t, __hip_bfloat16* wqkv_t, __hip_bfloat16* wo_t,
    __hip_bfloat16* w1_t, __hip_bfloat16* w2_t, __hip_bfloat16* wpost_t) {
    __shared__ float tile[64][65];
    int tb = blockIdx.x;
    if (tb >= 2400) {               // qkv bias concat: 6 blocks
        int l = tb - 2400;
        for (int i = threadIdx.x; i < 512; i += 256) {
            qkvbias[l * QKVLD + i]        = bq[l * DMODEL + i];
            qkvbias[l * QKVLD + 512 + i]  = bk[l * DMODEL + i];
            qkvbias[l * QKVLD + 1024 + i] = bv[l * DMODEL + i];
        }
        return;
    }
    const float* src; __hip_bfloat16* dst; int K, Kpad, kt, nt;
    if (tb < 32) {
        src = W_pre; dst = wpre_t; K = FIN; Kpad = FINPAD;
        kt = tb >> 3; nt = tb & 7;
    } else {
        int t2 = tb - 32; int mat = t2 >> 6; int tt = t2 & 63;
        kt = tt >> 3; nt = tt & 7; K = 512; Kpad = 512;
        if (mat == 36) { src = W_post; dst = wpost_t; }
        else {
            int l = mat / 6, j = mat % 6;
            const size_t WSZ = 262144;
            switch (j) {
                case 0: src = Wq + l * WSZ; dst = wqkv_t + l * 786432;          break;
                case 1: src = Wk + l * WSZ; dst = wqkv_t + l * 786432 + 262144; break;
                case 2: src = Wv + l * WSZ; dst = wqkv_t + l * 786432 + 524288; break;
                case 3: src = Wo + l * WSZ; dst = wo_t + l * WSZ;               break;
                case 4: src = W1 + l * WSZ; dst = w1_t + l * WSZ;               break;
                default: src = W2 + l * WSZ; dst = w2_t + l * WSZ;              break;
            }
        }
    }
    const int N = 512;
    int t = threadIdx.x;
    int k0 = kt * 64, n0 = nt * 64;
#pragma unroll
    for (int i = 0; i < 16; ++i) {
        int kk = (t >> 6) * 16 + i;
        int nn = t & 63;
        int k = k0 + kk;
        tile[kk][nn] = (k < K) ? src[(size_t)k * N + n0 + nn] : 0.f;
    }
    __syncthreads();
#pragma unroll
    for (int i = 0; i < 16; ++i) {
        int nn = (t >> 6) * 16 + i;
        int kk = t & 63;
        dst[(size_t)(n0 + nn) * Kpad + k0 + kk] = __float2bfloat16(tile[kk][nn]);
    }
}

// ---------------- megakernel params -----------------------------------------
struct MegaParams {
    const float *x, *g_in, *b_in, *b_pre, *bo, *bf1, *bf2;
    const float *ln1_g, *ln1_b, *ln2_g, *ln2_b, *lnf_g, *lnf_b, *b_post;
    const float* qkvbias;
    float *h, *t1, *ksumg, *out;
    __hip_bfloat16 *Sg, *hb, *qkvb, *xnb, *attb, *ffb, *t0b;
    const __hip_bfloat16 *wpre_t, *wqkv_t, *wo_t, *w1_t, *w2_t, *wpost_t;
};

// ---------------- the persistent cooperative megakernel ---------------------
__global__ __launch_bounds__(BLOCK, 2) void mega_kernel(MegaParams P) {
    __shared__ __align__(16) char smem[65536];
    cg::grid_group grid = cg::this_grid();

    ln_phase(P.x, P.g_in, P.b_in, nullptr, P.xnb, FIN, FINPAD);
    grid.sync();
    gemm_phase<0, 1, 1, 0, 0, FINPAD>(smem, P.xnb, P.wpre_t, P.b_pre,
                                      P.h, P.hb, nullptr, DMODEL);
    grid.sync();
    for (int l = 0; l < NLAYER; ++l) {
        gemm_phase<0, 0, 1, 1, 0, DMODEL>(smem, P.hb, P.wqkv_t + (size_t)l * 786432,
                                          P.qkvbias + l * QKVLD,
                                          nullptr, P.qkvb, nullptr, QKVLD);
        grid.sync();
        attnA_phase(smem, P.qkvb, P.Sg, P.ksumg);
        grid.sync();
        attnB_phase(smem, P.qkvb, P.Sg, P.ksumg, P.attb);
        grid.sync();
        gemm_phase<0, 1, 0, 0, 1, DMODEL>(smem, P.attb, P.wo_t + (size_t)l * 262144,
                                          P.bo + l * DMODEL, P.t1, nullptr, P.h, DMODEL);
        grid.sync();
        ln_phase(P.t1, P.ln1_g + l * DMODEL, P.ln1_b + l * DMODEL,
                 P.h, P.hb, DMODEL, DMODEL);
        grid.sync();
        gemm_phase<1, 0, 1, 0, 0, DMODEL>(smem, P.hb, P.w1_t + (size_t)l * 262144,
                                          P.bf1 + l * DMODEL, nullptr, P.ffb, nullptr, DMODEL);
        grid.sync();
        gemm_phase<0, 1, 0, 0, 1, DMODEL>(smem, P.ffb, P.w2_t + (size_t)l * 262144,
                                          P.bf2 + l * DMODEL, P.t1, nullptr, P.h, DMODEL);
        grid.sync();
        ln_phase(P.t1, P.ln2_g + l * DMODEL, P.ln2_b + l * DMODEL,
                 P.h, P.hb, DMODEL, DMODEL);
        grid.sync();
    }
    ln_phase(P.h, P.lnf_g, P.lnf_b, nullptr, P.t0b, DMODEL, DMODEL);
    grid.sync();
    gemm_phase<0, 1, 0, 0, 0, DMODEL>(smem, P.t0b, P.wpost_t, P.b_post,
                                      P.out, nullptr, nullptr, DMODEL);
}

// ---------------- standalone wrappers (fallback path) -----------------------
template<int RELU, int WF32, int WBF16, int PHI, int RES, int K>
__global__ __launch_bounds__(256) void k_gemm(
    const __hip_bfloat16* A, const __hip_bfloat16* Bt, const float* bias,
    float* C, __hip_bfloat16* Cb, const float* Rres, int N) {
    __shared__ __align__(16) char smem[65536];
    gemm_phase<RELU, WF32, WBF16, PHI, RES, K>(smem, A, Bt, bias, C, Cb, Rres, N);
}

__global__ __launch_bounds__(256) void k_ln(
    const float* in, const float* g, const float* b,
    float* out, __hip_bfloat16* outb, int C, int Cpad) {
    ln_phase(in, g, b, out, outb, C, Cpad);
}

__global__ __launch_bounds__(256) void k_attnA(
    const __hip_bfloat16* qkvb, __hip_bfloat16* Sg, float* ksumg) {
    __shared__ __align__(16) char smem[9216];
    attnA_phase(smem, qkvb, Sg, ksumg);
}

__global__ __launch_bounds__(256) void k_attnB(
    const __hip_bfloat16* qkvb, const __hip_bfloat16* Sg,
    const float* ksumg, __hip_bfloat16* out) {
    __shared__ __align__(16) char smem[27008];
    attnB_phase(smem, qkvb, Sg, ksumg, out);
}

// ---------------------------------------------------------------------------
extern "C" void kernel_launch(void* const* d_in, const int* in_sizes, int n_in,
                              void* d_out, int out_size, void* d_ws, size_t ws_size,
                              hipStream_t stream) {
    const float* x      = (const float*)d_in[0];
    const float* g_in   = (const float*)d_in[1];
    const float* b_in   = (const float*)d_in[2];
    const float* W_pre  = (const float*)d_in[3];
    const float* b_pre  = (const float*)d_in[4];
    const float* Wq     = (const float*)d_in[5];
    const float* bq     = (const float*)d_in[6];
    const float* Wk     = (const float*)d_in[7];
    const float* bk     = (const float*)d_in[8];
    const float* Wv     = (const float*)d_in[9];
    const float* bv     = (const float*)d_in[10];
    const float* Wo     = (const float*)d_in[11];
    const float* bo     = (const float*)d_in[12];
    const float* W1     = (const float*)d_in[13];
    const float* bf1    = (const float*)d_in[14];
    const float* W2     = (const float*)d_in[15];
    const float* bf2    = (const float*)d_in[16];
    const float* ln1_g  = (const float*)d_in[17];
    const float* ln1_b  = (const float*)d_in[18];
    const float* ln2_g  = (const float*)d_in[19];
    const float* ln2_b  = (const float*)d_in[20];
    const float* lnf_g  = (const float*)d_in[21];
    const float* lnf_b  = (const float*)d_in[22];
    const float* W_post = (const float*)d_in[23];
    const float* b_post = (const float*)d_in[24];
    (void)in_sizes; (void)n_in; (void)out_size; (void)ws_size;

    float* ws = (float*)d_ws;
    const size_t SZ = (size_t)NROW * DMODEL;          // 1048576
    float* h       = ws;
    float* t1      = h + SZ;
    float* ksumg   = t1 + SZ;                         // 16384
    float* qkvbias = ksumg + 16384;                   // 9216
    __hip_bfloat16* bp = (__hip_bfloat16*)(qkvbias + 9216);
    __hip_bfloat16* Sg     = bp;            bp += 524288;
    __hip_bfloat16* hb     = bp;            bp += SZ;
    __hip_bfloat16* qkvb   = bp;            bp += (size_t)NROW * QKVLD;
    __hip_bfloat16* xnb    = bp;            bp += (size_t)NROW * FINPAD;
    __hip_bfloat16* attb   = bp;            bp += SZ;
    __hip_bfloat16* ffb    = bp;            bp += SZ;
    __hip_bfloat16* t0b    = bp;            bp += SZ;
    __hip_bfloat16* wpre_t = bp;            bp += (size_t)DMODEL * FINPAD;
    __hip_bfloat16* wqkv_t = bp;            bp += (size_t)NLAYER * 786432;
    __hip_bfloat16* wo_t   = bp;            bp += (size_t)NLAYER * 262144;
    __hip_bfloat16* w1_t   = bp;            bp += (size_t)NLAYER * 262144;
    __hip_bfloat16* w2_t   = bp;            bp += (size_t)NLAYER * 262144;
    __hip_bfloat16* wpost_t= bp;

    // weight conversion + qkv bias concat (normal kernel, same stream)
    wconv_kernel<<<2406, 256, 0, stream>>>(
        W_pre, Wq, Wk, Wv, Wo, W1, W2, W_post,
        bq, bk, bv, qkvbias,
        wpre_t, wqkv_t, wo_t, w1_t, w2_t, wpost_t);

    MegaParams P;
    P.x = x; P.g_in = g_in; P.b_in = b_in; P.b_pre = b_pre;
    P.bo = bo; P.bf1 = bf1; P.bf2 = bf2;
    P.ln1_g = ln1_g; P.ln1_b = ln1_b; P.ln2_g = ln2_g; P.ln2_b = ln2_b;
    P.lnf_g = lnf_g; P.lnf_b = lnf_b; P.b_post = b_post;
    P.qkvbias = qkvbias;
    P.h = h; P.t1 = t1; P.ksumg = ksumg; P.out = (float*)d_out;
    P.Sg = Sg; P.hb = hb; P.qkvb = qkvb; P.xnb = xnb;
    P.attb = attb; P.ffb = ffb; P.t0b = t0b;
    P.wpre_t = wpre_t; P.wqkv_t = wqkv_t; P.wo_t = wo_t;
    P.w1_t = w1_t; P.w2_t = w2_t; P.wpost_t = wpost_t;

    int coop = 0;
    (void)hipDeviceGetAttribute(&coop, hipDeviceAttributeCooperativeLaunch, 0);
    hipError_t err = hipErrorUnknown;
    if (coop) {
        void* kargs[] = { (void*)&P };
        err = hipLaunchCooperativeKernel(reinterpret_cast<void*>(mega_kernel),
                                         dim3(GRID), dim3(BLOCK), kargs, 0, stream);
    }
    if (err != hipSuccess) {
        // fallback: identical phases as ordinary kernels (stream-ordered)
        k_ln<<<GRID, BLOCK, 0, stream>>>(x, g_in, b_in, nullptr, xnb, FIN, FINPAD);
        k_gemm<0, 1, 1, 0, 0, FINPAD><<<GRID, BLOCK, 0, stream>>>(
            xnb, wpre_t, b_pre, h, hb, nullptr, DMODEL);
        for (int l = 0; l < NLAYER; ++l) {
            k_gemm<0, 0, 1, 1, 0, DMODEL><<<GRID, BLOCK, 0, stream>>>(
                hb, wqkv_t + (size_t)l * 786432, qkvbias + l * QKVLD,
                nullptr, qkvb, nullptr, QKVLD);
            k_attnA<<<GRID, BLOCK, 0, stream>>>(qkvb, Sg, ksumg);
            k_attnB<<<GRID, BLOCK, 0, stream>>>(qkvb, Sg, ksumg, attb);
            k_gemm<0, 1, 0, 0, 1, DMODEL><<<GRID, BLOCK, 0, stream>>>(
                attb, wo_t + (size_t)l * 262144, bo + l * DMODEL,
                t1, nullptr, h, DMODEL);
            k_ln<<<GRID, BLOCK, 0, stream>>>(t1, ln1_g + l * DMODEL, ln1_b + l * DMODEL,
                                             h, hb, DMODEL, DMODEL);
            k_gemm<1, 0, 1, 0, 0, DMODEL><<<GRID, BLOCK, 0, stream>>>(
                hb, w1_t + (size_t)l * 262144, bf1 + l * DMODEL,
                nullptr, ffb, nullptr, DMODEL);
            k_gemm<0, 1, 0, 0, 1, DMODEL><<<GRID, BLOCK, 0, stream>>>(
                ffb, w2_t + (size_t)l * 262144, bf2 + l * DMODEL,
                t1, nullptr, h, DMODEL);
            k_ln<<<GRID, BLOCK, 0, stream>>>(t1, ln2_g + l * DMODEL, ln2_b + l * DMODEL,
                                             h, hb, DMODEL, DMODEL);
        }
        k_ln<<<GRID, BLOCK, 0, stream>>>(h, lnf_g, lnf_b, nullptr, t0b, DMODEL, DMODEL);
        k_gemm<0, 1, 0, 0, 0, DMODEL><<<GRID, BLOCK, 0, stream>>>(
            t0b, wpost_t, b_post, (float*)d_out, nullptr, nullptr, DMODEL);
    }
}

// Round 13
// 344.906 us; speedup vs baseline: 9.4878x; 9.4878x over previous
//
#include <hip/hip_runtime.h>
#include <hip/hip_bf16.h>
#include <cmath>

#define NROW 2048      // B*S
#define DMODEL 512
#define FIN 240
#define FINPAD 256
#define NHEAD 16
#define DHEAD 32
#define CHUNK 64
#define NCHUNK 16      // S / CHUNK
#define NLAYER 6
#define SEQ 1024
#define QKVLD 1536

typedef __attribute__((ext_vector_type(8))) short bf16x8;
typedef __attribute__((ext_vector_type(4))) float f32x4;
typedef __attribute__((ext_vector_type(4))) unsigned short u16x4;

#define MFMA_BF16 __builtin_amdgcn_mfma_f32_16x16x32_bf16

// phi(x) = elu(x) + 1
__device__ __forceinline__ float phi(float x) {
    return x > 0.f ? x + 1.f : expf(x);
}

__device__ __forceinline__ float bf2f(unsigned short u) {
    return __uint_as_float((unsigned)u << 16);
}

__device__ __forceinline__ unsigned short f2bf_bits(float z) {
    __hip_bfloat16 hb_ = __float2bfloat16(z);
    return *reinterpret_cast<unsigned short*>(&hb_);
}

__device__ __forceinline__ void load_lds16(const void* g, void* l) {
    __builtin_amdgcn_global_load_lds(
        (const __attribute__((address_space(1))) void*)g,
        (__attribute__((address_space(3))) void*)l, 16, 0, 0);
}

// ---------------- LayerNorm, 1 wave/row, float4 loads, shfl-only reduce ----
// C <= 512 (multiple of 4), Cpad <= 512
__global__ __launch_bounds__(64) void ln_kernel(
    const float* __restrict__ in, const float* __restrict__ res,
    const float* __restrict__ g, const float* __restrict__ b,
    float* __restrict__ out, __hip_bfloat16* __restrict__ outb,
    int C, int Cpad) {
    int row = blockIdx.x;
    int t = threadIdx.x;
    const float* xr = in + (size_t)row * C;
    const float* rr = res ? res + (size_t)row * C : nullptr;
    f32x4 v[2] = {{0.f,0.f,0.f,0.f},{0.f,0.f,0.f,0.f}};
    float sum = 0.f, sq = 0.f;
#pragma unroll
    for (int i = 0; i < 2; ++i) {
        int c = (t + i * 64) * 4;
        if (c < C) {
            f32x4 x_ = *(const f32x4*)&xr[c];
            if (rr) x_ += *(const f32x4*)&rr[c];
            v[i] = x_;
#pragma unroll
            for (int j = 0; j < 4; ++j) { sum += x_[j]; sq += x_[j] * x_[j]; }
        }
    }
#pragma unroll
    for (int off = 32; off > 0; off >>= 1) {
        sum += __shfl_xor(sum, off, 64);
        sq  += __shfl_xor(sq,  off, 64);
    }
    float mean = sum / (float)C;
    float var  = sq / (float)C - mean * mean;
    float rstd = rsqrtf(var + 1e-5f);
#pragma unroll
    for (int i = 0; i < 2; ++i) {
        int c = (t + i * 64) * 4;
        f32x4 y;
#pragma unroll
        for (int j = 0; j < 4; ++j) y[j] = (v[i][j] - mean) * rstd;
        if (c < C) {
            f32x4 gg = *(const f32x4*)&g[c];
            f32x4 bb = *(const f32x4*)&b[c];
#pragma unroll
            for (int j = 0; j < 4; ++j) y[j] = y[j] * gg[j] + bb[j];
            if (out) *(f32x4*)&out[(size_t)row * C + c] = y;
        }
        if (outb && c < Cpad) {
            u16x4 o;
#pragma unroll
            for (int j = 0; j < 4; ++j) {
                float z = (c + j < C) ? y[j] : 0.f;
                o[j] = f2bf_bits(z);
            }
            *(u16x4*)&outb[(size_t)row * Cpad + c] = o;
        }
    }
}

// ---------------- bf16 MFMA GEMM, 64x64 tile, counted-vmcnt ring pipeline ---
// C = A[M,K] * Bt[N,K]^T + bias. BM=BN=64, BK=64, ring-4 LDS buffers (64 KB),
// 4 waves 2x2, wave tile 32x32 (2x2 frags -> 8 MFMA : 8 ds_read per step).
// Pre-swizzled global_load_lds staging; vmcnt(8/4/0), never 0 mid-loop.
template<int RELU, int WF32, int WBF16, int PHI, int K>
__global__ __launch_bounds__(256) void gemm_bf16_kernel(
    const __hip_bfloat16* __restrict__ A, const __hip_bfloat16* __restrict__ Bt,
    const float* __restrict__ bias,
    float* __restrict__ C, __hip_bfloat16* __restrict__ Cb,
    int N) {
    constexpr int NSTEP = K / 64;
    __shared__ __align__(16) __hip_bfloat16 As[4][64][64];
    __shared__ __align__(16) __hip_bfloat16 Bs[4][64][64];
    const int tid = threadIdx.x, lane = tid & 63, w = tid >> 6;
    const int nN = N >> 6;
    const int bm = (blockIdx.x / nN) * 64;
    const int bn = (blockIdx.x % nN) * 64;

    // staging: instr i of matrix covers rows i*32 + w*8 + (lane>>3), slot lane&7
    const int srow  = lane >> 3;                 // 0..7
    const int sslot = (lane & 7) ^ srow;         // pre-swizzled global slot
    const size_t aoff = (size_t)srow * K + (size_t)sslot * 8;
    const __hip_bfloat16* gA0 = A  + (size_t)(bm + w * 8) * K + aoff;
    const __hip_bfloat16* gA1 = A  + (size_t)(bm + 32 + w * 8) * K + aoff;
    const __hip_bfloat16* gB0 = Bt + (size_t)(bn + w * 8) * K + aoff;
    const __hip_bfloat16* gB1 = Bt + (size_t)(bn + 32 + w * 8) * K + aoff;

#define STAGE(t) do { \
        load_lds16(gA0 + (size_t)(t) * 64, &As[(t) & 3][w * 8][0]); \
        load_lds16(gA1 + (size_t)(t) * 64, &As[(t) & 3][32 + w * 8][0]); \
        load_lds16(gB0 + (size_t)(t) * 64, &Bs[(t) & 3][w * 8][0]); \
        load_lds16(gB1 + (size_t)(t) * 64, &Bs[(t) & 3][32 + w * 8][0]); \
    } while (0)

    const int wm = (w >> 1) << 5, wn = (w & 1) << 5;
    const int fr = lane & 15, fq = lane >> 4;
    const int sw = fr & 7;
    const int e0 = ((fq      ^ sw) << 3);        // k-half 0 slot (swizzled)
    const int e1 = (((fq | 4) ^ sw) << 3);       // k-half 1 slot
    f32x4 acc00 = {0.f, 0.f, 0.f, 0.f}, acc01 = acc00, acc10 = acc00, acc11 = acc00;

    STAGE(0); STAGE(1); STAGE(2);
#pragma unroll
    for (int t = 0; t < NSTEP; ++t) {
        if (NSTEP - t >= 3)      asm volatile("s_waitcnt vmcnt(8)" ::: "memory");
        else if (NSTEP - t == 2) asm volatile("s_waitcnt vmcnt(4)" ::: "memory");
        else                     asm volatile("s_waitcnt vmcnt(0)" ::: "memory");
        __builtin_amdgcn_s_barrier();
        __builtin_amdgcn_sched_barrier(0);
        if (t + 3 < NSTEP) STAGE(t + 3);
        const int b = t & 3;
        bf16x8 a00 = *(const bf16x8*)&As[b][wm + fr][e0];
        bf16x8 a01 = *(const bf16x8*)&As[b][wm + fr][e1];
        bf16x8 a10 = *(const bf16x8*)&As[b][wm + 16 + fr][e0];
        bf16x8 a11 = *(const bf16x8*)&As[b][wm + 16 + fr][e1];
        bf16x8 b00 = *(const bf16x8*)&Bs[b][wn + fr][e0];
        bf16x8 b01 = *(const bf16x8*)&Bs[b][wn + fr][e1];
        bf16x8 b10 = *(const bf16x8*)&Bs[b][wn + 16 + fr][e0];
        bf16x8 b11 = *(const bf16x8*)&Bs[b][wn + 16 + fr][e1];
        acc00 = MFMA_BF16(a00, b00, acc00, 0, 0, 0);
        acc01 = MFMA_BF16(a00, b10, acc01, 0, 0, 0);
        acc10 = MFMA_BF16(a10, b00, acc10, 0, 0, 0);
        acc11 = MFMA_BF16(a10, b10, acc11, 0, 0, 0);
        acc00 = MFMA_BF16(a01, b01, acc00, 0, 0, 0);
        acc01 = MFMA_BF16(a01, b11, acc01, 0, 0, 0);
        acc10 = MFMA_BF16(a11, b01, acc10, 0, 0, 0);
        acc11 = MFMA_BF16(a11, b11, acc11, 0, 0, 0);
    }
#undef STAGE

    const int orow = bm + wm + (fq << 2);
    const int ocol = bn + wn + fr;
    float bv0 = bias[ocol], bv1 = bias[ocol + 16];
    f32x4 accs[2][2] = {{acc00, acc01}, {acc10, acc11}};
#pragma unroll
    for (int i = 0; i < 2; ++i)
#pragma unroll
        for (int r = 0; r < 4; ++r) {
            int row = orow + i * 16 + r;
            float v0 = accs[i][0][r] + bv0;
            float v1 = accs[i][1][r] + bv1;
            if (RELU) { v0 = fmaxf(v0, 0.f); v1 = fmaxf(v1, 0.f); }
            if (PHI) {
                if (ocol < 1024)      v0 = phi(v0);
                if (ocol + 16 < 1024) v1 = phi(v1);
            }
            if (WF32) {
                C[(size_t)row * N + ocol]      = v0;
                C[(size_t)row * N + ocol + 16] = v1;
            }
            if (WBF16) {
                Cb[(size_t)row * N + ocol]      = __float2bfloat16(v0);
                Cb[(size_t)row * N + ocol + 16] = __float2bfloat16(v1);
            }
        }
}

// ---------------- weight transpose + bf16 convert (+ qkv bias concat) -------
__global__ __launch_bounds__(256) void wconv_kernel(
    const float* __restrict__ W_pre, const float* __restrict__ Wq,
    const float* __restrict__ Wk, const float* __restrict__ Wv,
    const float* __restrict__ Wo, const float* __restrict__ W1,
    const float* __restrict__ W2, const float* __restrict__ W_post,
    const float* __restrict__ bq, const float* __restrict__ bk,
    const float* __restrict__ bv, float* __restrict__ qkvbias,
    __hip_bfloat16* wpre_t, __hip_bfloat16* wqkv_t, __hip_bfloat16* wo_t,
    __hip_bfloat16* w1_t, __hip_bfloat16* w2_t, __hip_bfloat16* wpost_t) {
    __shared__ float tile[64][65];
    int tb = blockIdx.x;
    if (tb >= 2400) {               // qkv bias concat: 6 blocks
        int l = tb - 2400;
        for (int i = threadIdx.x; i < 512; i += 256) {
            qkvbias[l * QKVLD + i]        = bq[l * DMODEL + i];
            qkvbias[l * QKVLD + 512 + i]  = bk[l * DMODEL + i];
            qkvbias[l * QKVLD + 1024 + i] = bv[l * DMODEL + i];
        }
        return;
    }
    const float* src; __hip_bfloat16* dst; int K, Kpad, kt, nt;
    if (tb < 32) {
        src = W_pre; dst = wpre_t; K = FIN; Kpad = FINPAD;
        kt = tb >> 3; nt = tb & 7;
    } else {
        int t2 = tb - 32; int mat = t2 >> 6; int tt = t2 & 63;
        kt = tt >> 3; nt = tt & 7; K = 512; Kpad = 512;
        if (mat == 36) { src = W_post; dst = wpost_t; }
        else {
            int l = mat / 6, j = mat % 6;
            const size_t WSZ = 262144;
            switch (j) {
                case 0: src = Wq + l * WSZ; dst = wqkv_t + l * 786432;          break;
                case 1: src = Wk + l * WSZ; dst = wqkv_t + l * 786432 + 262144; break;
                case 2: src = Wv + l * WSZ; dst = wqkv_t + l * 786432 + 524288; break;
                case 3: src = Wo + l * WSZ; dst = wo_t + l * WSZ;               break;
                case 4: src = W1 + l * WSZ; dst = w1_t + l * WSZ;               break;
                default: src = W2 + l * WSZ; dst = w2_t + l * WSZ;              break;
            }
        }
    }
    const int N = 512;
    int t = threadIdx.x;
    int k0 = kt * 64, n0 = nt * 64;
#pragma unroll
    for (int i = 0; i < 16; ++i) {
        int kk = (t >> 6) * 16 + i;
        int nn = t & 63;
        int k = k0 + kk;
        tile[kk][nn] = (k < K) ? src[(size_t)k * N + n0 + nn] : 0.f;
    }
    __syncthreads();
#pragma unroll
    for (int i = 0; i < 16; ++i) {
        int nn = (t >> 6) * 16 + i;
        int kk = t & 63;
        dst[(size_t)(n0 + nn) * Kpad + k0 + kk] = __float2bfloat16(tile[kk][nn]);
    }
}

// ---------------- attention phase A: S_c = V^T K (32x32, bf16 out) + ksum --
// grid (NCHUNK, NHEAD, B), 64 threads. qkvb: bf16 [2048][1536], Q|phi, K|phi, V.
__global__ __launch_bounds__(64) void attn_state_kernel(
    const __hip_bfloat16* __restrict__ qkvb,
    __hip_bfloat16* __restrict__ Sg, float* __restrict__ ksumg) {
    __shared__ __hip_bfloat16 Kt[32][72];
    __shared__ __hip_bfloat16 Vt[32][72];
    int c = blockIdx.x, hh = blockIdx.y, b = blockIdx.z;
    int t = threadIdx.x;
    int sub = t >> 2, slot = t & 3;
    size_t rb = ((size_t)(b * SEQ + c * CHUNK)) * QKVLD + hh * DHEAD;
#pragma unroll
    for (int it = 0; it < 4; ++it) {
        int s = it * 16 + sub;
        bf16x8 kv = *(const bf16x8*)&qkvb[rb + (size_t)s * QKVLD + 512 + slot * 8];
        bf16x8 vv = *(const bf16x8*)&qkvb[rb + (size_t)s * QKVLD + 1024 + slot * 8];
#pragma unroll
        for (int i = 0; i < 8; ++i) {
            Kt[slot * 8 + i][s] = ((const __hip_bfloat16*)&kv)[i];
            Vt[slot * 8 + i][s] = ((const __hip_bfloat16*)&vv)[i];
        }
    }
    __syncthreads();
    int fr = t & 15, fq = t >> 4;
    f32x4 a00 = {0.f,0.f,0.f,0.f}, a01 = a00, a10 = a00, a11 = a00;
#pragma unroll
    for (int ks = 0; ks < 2; ++ks) {
        bf16x8 v0 = *(const bf16x8*)&Vt[fr][ks * 32 + fq * 8];
        bf16x8 v1 = *(const bf16x8*)&Vt[16 + fr][ks * 32 + fq * 8];
        bf16x8 k0 = *(const bf16x8*)&Kt[fr][ks * 32 + fq * 8];
        bf16x8 k1 = *(const bf16x8*)&Kt[16 + fr][ks * 32 + fq * 8];
        a00 = MFMA_BF16(v0, k0, a00, 0, 0, 0);
        a01 = MFMA_BF16(v0, k1, a01, 0, 0, 0);
        a10 = MFMA_BF16(v1, k0, a10, 0, 0, 0);
        a11 = MFMA_BF16(v1, k1, a11, 0, 0, 0);
    }
    size_t ob = ((size_t)((b * NHEAD + hh) * NCHUNK + c)) * 1024;
#pragma unroll
    for (int r = 0; r < 4; ++r) {
        int m0 = fq * 4 + r;
        Sg[ob + (size_t)m0 * 32 + fr]             = __float2bfloat16(a00[r]);
        Sg[ob + (size_t)m0 * 32 + 16 + fr]        = __float2bfloat16(a01[r]);
        Sg[ob + (size_t)(16 + m0) * 32 + fr]      = __float2bfloat16(a10[r]);
        Sg[ob + (size_t)(16 + m0) * 32 + 16 + fr] = __float2bfloat16(a11[r]);
    }
    if (t < 32) {
        float s_ = 0.f;
        for (int s = 0; s < CHUNK; ++s) s_ += __bfloat162float(Kt[t][s]);
        ksumg[((size_t)((b * NHEAD + hh) * NCHUNK + c)) * 32 + t] = s_;
    }
}

// ---------------- attention phase B: intra-chunk (MFMA) + state + output ---
// grid (NCHUNK, NHEAD, B), 256 threads (4 waves; wave w owns rows w*16..+15).
__global__ __launch_bounds__(256) void attn_out_kernel(
    const __hip_bfloat16* __restrict__ qkvb,
    const __hip_bfloat16* __restrict__ Sg, const float* __restrict__ ksumg,
    __hip_bfloat16* __restrict__ out) {
    __shared__ __hip_bfloat16 Qs[64][40];
    __shared__ __hip_bfloat16 Ks[64][40];
    __shared__ __hip_bfloat16 Vt[32][72];
    __shared__ __hip_bfloat16 Awb[64][72];
    __shared__ __hip_bfloat16 Stb[32][40];
    __shared__ float den[64];
    __shared__ float ksml[32];
    int c = blockIdx.x, hh = blockIdx.y, b = blockIdx.z;
    int tid = threadIdx.x, lane = tid & 63, w = tid >> 6;
    size_t rb = ((size_t)(b * SEQ + c * CHUNK)) * QKVLD + hh * DHEAD;
    {
        int row = tid >> 2, slot = tid & 3;
        *(bf16x8*)&Qs[row][slot * 8] =
            *(const bf16x8*)&qkvb[rb + (size_t)row * QKVLD + slot * 8];
        *(bf16x8*)&Ks[row][slot * 8] =
            *(const bf16x8*)&qkvb[rb + (size_t)row * QKVLD + 512 + slot * 8];
        bf16x8 vv = *(const bf16x8*)&qkvb[rb + (size_t)row * QKVLD + 1024 + slot * 8];
#pragma unroll
        for (int i = 0; i < 8; ++i)
            Vt[slot * 8 + i][row] = ((const __hip_bfloat16*)&vv)[i];
    }
    // state prefix (sum of prior chunks' S, bf16 chunks, fp32 accumulate)
    size_t sb = ((size_t)((b * NHEAD + hh) * NCHUNK)) * 1024;
    {
        f32x4 st = {0.f, 0.f, 0.f, 0.f};
        for (int cp = 0; cp < c; ++cp) {
            u16x4 sv = *(const u16x4*)&Sg[sb + (size_t)cp * 1024 + tid * 4];
#pragma unroll
            for (int i = 0; i < 4; ++i) st[i] += bf2f(sv[i]);
        }
        int m = tid >> 3, d0 = (tid & 7) * 4;
#pragma unroll
        for (int i = 0; i < 4; ++i) Stb[m][d0 + i] = __float2bfloat16(st[i]);
    }
    if (tid < 32) {
        size_t kb = ((size_t)((b * NHEAD + hh) * NCHUNK)) * 32;
        float s_ = 0.f;
        for (int cp = 0; cp < c; ++cp) s_ += ksumg[kb + cp * 32 + tid];
        ksml[tid] = s_;
    }
    __syncthreads();
    int fr = lane & 15, fq = lane >> 4;
    bf16x8 aQ = *(const bf16x8*)&Qs[w * 16 + fr][fq * 8];
    f32x4 p[4];
#pragma unroll
    for (int j = 0; j < 4; ++j) {
        f32x4 z = {0.f, 0.f, 0.f, 0.f};
        bf16x8 bK = *(const bf16x8*)&Ks[j * 16 + fr][fq * 8];
        p[j] = MFMA_BF16(aQ, bK, z, 0, 0, 0);
    }
    // causal mask + row sums (denominator, fp32)
    float rs[4] = {0.f, 0.f, 0.f, 0.f};
#pragma unroll
    for (int j = 0; j < 4; ++j) {
        int tcol = j * 16 + fr;
#pragma unroll
        for (int r = 0; r < 4; ++r) {
            int s = w * 16 + fq * 4 + r;
            float val = (tcol <= s) ? p[j][r] : 0.f;
            p[j][r] = val;
            rs[r] += val;
        }
    }
#pragma unroll
    for (int off = 8; off > 0; off >>= 1) {
#pragma unroll
        for (int r = 0; r < 4; ++r) rs[r] += __shfl_xor(rs[r], off, 64);
    }
    if (fr == 0) {
#pragma unroll
        for (int r = 0; r < 4; ++r) den[w * 16 + fq * 4 + r] = rs[r];
    }
#pragma unroll
    for (int j = 0; j < 4; ++j)
#pragma unroll
        for (int r = 0; r < 4; ++r)
            Awb[w * 16 + fq * 4 + r][j * 16 + fr] = __float2bfloat16(p[j][r]);
    __syncthreads();
    if (tid < 64) {
        float dq = den[tid];
        float dst_ = 0.f;
#pragma unroll
        for (int d = 0; d < 32; ++d)
            dst_ += __bfloat162float(Qs[tid][d]) * ksml[d];
        den[tid] = 1.f / (dq + dst_ + 1e-6f);
    }
    __syncthreads();
    size_t orb = ((size_t)(b * SEQ + c * CHUNK)) * DMODEL + hh * DHEAD;
#pragma unroll
    for (int mf = 0; mf < 2; ++mf) {
        f32x4 acc = {0.f, 0.f, 0.f, 0.f};
        bf16x8 bS = *(const bf16x8*)&Stb[mf * 16 + fr][fq * 8];
        acc = MFMA_BF16(aQ, bS, acc, 0, 0, 0);
#pragma unroll
        for (int ks = 0; ks < 2; ++ks) {
            bf16x8 aA = *(const bf16x8*)&Awb[w * 16 + fr][ks * 32 + fq * 8];
            bf16x8 bV = *(const bf16x8*)&Vt[mf * 16 + fr][ks * 32 + fq * 8];
            acc = MFMA_BF16(aA, bV, acc, 0, 0, 0);
        }
#pragma unroll
        for (int r = 0; r < 4; ++r) {
            int s = w * 16 + fq * 4 + r;
            out[orb + (size_t)s * DMODEL + mf * 16 + fr] =
                __float2bfloat16(acc[r] * den[s]);
        }
    }
}

// ---------------------------------------------------------------------------
template<int R, int WF, int WB, int PHI, int K>
static inline void gemm(const __hip_bfloat16* A, const __hip_bfloat16* Bt,
                        const float* bias, float* C, __hip_bfloat16* Cb,
                        int M, int N, hipStream_t s) {
    gemm_bf16_kernel<R, WF, WB, PHI, K><<<(M / 64) * (N / 64), 256, 0, s>>>(A, Bt, bias, C, Cb, N);
}

extern "C" void kernel_launch(void* const* d_in, const int* in_sizes, int n_in,
                              void* d_out, int out_size, void* d_ws, size_t ws_size,
                              hipStream_t stream) {
    const float* x      = (const float*)d_in[0];
    const float* g_in   = (const float*)d_in[1];
    const float* b_in   = (const float*)d_in[2];
    const float* W_pre  = (const float*)d_in[3];
    const float* b_pre  = (const float*)d_in[4];
    const float* Wq     = (const float*)d_in[5];
    const float* bq     = (const float*)d_in[6];
    const float* Wk     = (const float*)d_in[7];
    const float* bk     = (const float*)d_in[8];
    const float* Wv     = (const float*)d_in[9];
    const float* bv     = (const float*)d_in[10];
    const float* Wo     = (const float*)d_in[11];
    const float* bo     = (const float*)d_in[12];
    const float* W1     = (const float*)d_in[13];
    const float* bf1    = (const float*)d_in[14];
    const float* W2     = (const float*)d_in[15];
    const float* bf2    = (const float*)d_in[16];
    const float* ln1_g  = (const float*)d_in[17];
    const float* ln1_b  = (const float*)d_in[18];
    const float* ln2_g  = (const float*)d_in[19];
    const float* ln2_b  = (const float*)d_in[20];
    const float* lnf_g  = (const float*)d_in[21];
    const float* lnf_b  = (const float*)d_in[22];
    const float* W_post = (const float*)d_in[23];
    const float* b_post = (const float*)d_in[24];
    (void)in_sizes; (void)n_in; (void)out_size; (void)ws_size;

    float* ws = (float*)d_ws;
    const size_t SZ = (size_t)NROW * DMODEL;          // 1048576
    float* h       = ws;
    float* t1      = h + SZ;
    float* ksumg   = t1 + SZ;                         // 16384
    float* qkvbias = ksumg + 16384;                   // 9216
    __hip_bfloat16* bp = (__hip_bfloat16*)(qkvbias + 9216);
    __hip_bfloat16* Sg     = bp;            bp += 524288;                  // bf16 state chunks
    __hip_bfloat16* hb     = bp;            bp += SZ;
    __hip_bfloat16* qkvb   = bp;            bp += (size_t)NROW * QKVLD;    // 3145728
    __hip_bfloat16* xnb    = bp;            bp += (size_t)NROW * FINPAD;   // 524288
    __hip_bfloat16* attb   = bp;            bp += SZ;
    __hip_bfloat16* ffb    = bp;            bp += SZ;
    __hip_bfloat16* t0b    = bp;            bp += SZ;
    __hip_bfloat16* wpre_t = bp;            bp += (size_t)DMODEL * FINPAD; // 131072
    __hip_bfloat16* wqkv_t = bp;            bp += (size_t)NLAYER * 786432;
    __hip_bfloat16* wo_t   = bp;            bp += (size_t)NLAYER * 262144;
    __hip_bfloat16* w1_t   = bp;            bp += (size_t)NLAYER * 262144;
    __hip_bfloat16* w2_t   = bp;            bp += (size_t)NLAYER * 262144;
    __hip_bfloat16* wpost_t= bp;

    // one-time-per-call weight conversion + qkv bias concat
    wconv_kernel<<<2406, 256, 0, stream>>>(
        W_pre, Wq, Wk, Wv, Wo, W1, W2, W_post,
        bq, bk, bv, qkvbias,
        wpre_t, wqkv_t, wo_t, w1_t, w2_t, wpost_t);

    // input LN (bf16, K padded 240->256) + pre projection (h fp32 + hb bf16)
    ln_kernel<<<NROW, 64, 0, stream>>>(x, nullptr, g_in, b_in, nullptr, xnb, FIN, FINPAD);
    gemm<0, 1, 1, 0, FINPAD>(xnb, wpre_t, b_pre, h, hb, NROW, DMODEL, stream);

    dim3 ag(NCHUNK, NHEAD, 2);
    for (int l = 0; l < NLAYER; ++l) {
        // fused QKV projection -> bf16 [2048][1536], phi applied to Q,K cols
        gemm<0, 0, 1, 1, DMODEL>(hb, wqkv_t + (size_t)l * 786432, qkvbias + l * QKVLD,
                                 nullptr, qkvb, NROW, QKVLD, stream);
        attn_state_kernel<<<ag, 64, 0, stream>>>(qkvb, Sg, ksumg);
        attn_out_kernel<<<ag, 256, 0, stream>>>(qkvb, Sg, ksumg, attb);
        gemm<0, 1, 0, 0, DMODEL>(attb, wo_t + (size_t)l * 262144, bo + l * DMODEL,
                                 t1, nullptr, NROW, DMODEL, stream);
        ln_kernel<<<NROW, 64, 0, stream>>>(h, t1, ln1_g + l * DMODEL, ln1_b + l * DMODEL,
                                           h, hb, DMODEL, DMODEL);
        gemm<1, 0, 1, 0, DMODEL>(hb, w1_t + (size_t)l * 262144, bf1 + l * DMODEL,
                                 nullptr, ffb, NROW, DMODEL, stream);
        gemm<0, 1, 0, 0, DMODEL>(ffb, w2_t + (size_t)l * 262144, bf2 + l * DMODEL,
                                 t1, nullptr, NROW, DMODEL, stream);
        ln_kernel<<<NROW, 64, 0, stream>>>(h, t1, ln2_g + l * DMODEL, ln2_b + l * DMODEL,
                                           h, hb, DMODEL, DMODEL);
    }

    // final LN (bf16 only) + post projection (fp32 to d_out)
    ln_kernel<<<NROW, 64, 0, stream>>>(h, nullptr, lnf_g, lnf_b, nullptr, t0b, DMODEL, DMODEL);
    gemm<0, 1, 0, 0, DMODEL>(t0b, wpost_t, b_post, (float*)d_out, nullptr, NROW, DMODEL, stream);
}

// Round 14
// 341.037 us; speedup vs baseline: 9.5955x; 1.0113x over previous
//
#include <hip/hip_runtime.h>
#include <hip/hip_bf16.h>
#include <cmath>

#define NROW 2048      // B*S
#define DMODEL 512
#define FIN 240
#define FINPAD 256
#define NHEAD 16
#define DHEAD 32
#define CHUNK 64
#define NCHUNK 16      // S / CHUNK
#define NLAYER 6
#define SEQ 1024
#define QKVLD 1536

typedef __attribute__((ext_vector_type(8))) short bf16x8;
typedef __attribute__((ext_vector_type(4))) float f32x4;
typedef __attribute__((ext_vector_type(4))) unsigned short u16x4;

#define MFMA_BF16 __builtin_amdgcn_mfma_f32_16x16x32_bf16

// phi(x) = elu(x) + 1
__device__ __forceinline__ float phi(float x) {
    return x > 0.f ? x + 1.f : expf(x);
}

__device__ __forceinline__ float bf2f(unsigned short u) {
    return __uint_as_float((unsigned)u << 16);
}

__device__ __forceinline__ unsigned short f2bf_bits(float z) {
    __hip_bfloat16 hb_ = __float2bfloat16(z);
    return *reinterpret_cast<unsigned short*>(&hb_);
}

__device__ __forceinline__ void load_lds16(const void* g, void* l) {
    __builtin_amdgcn_global_load_lds(
        (const __attribute__((address_space(1))) void*)g,
        (__attribute__((address_space(3))) void*)l, 16, 0, 0);
}

// ---------------- LayerNorm, 1 wave/row, float4 loads, shfl-only reduce ----
// C <= 512 (multiple of 4), Cpad <= 512
__global__ __launch_bounds__(64) void ln_kernel(
    const float* __restrict__ in, const float* __restrict__ res,
    const float* __restrict__ g, const float* __restrict__ b,
    float* __restrict__ out, __hip_bfloat16* __restrict__ outb,
    int C, int Cpad) {
    int row = blockIdx.x;
    int t = threadIdx.x;
    const float* xr = in + (size_t)row * C;
    const float* rr = res ? res + (size_t)row * C : nullptr;
    f32x4 v[2] = {{0.f,0.f,0.f,0.f},{0.f,0.f,0.f,0.f}};
    float sum = 0.f, sq = 0.f;
#pragma unroll
    for (int i = 0; i < 2; ++i) {
        int c = (t + i * 64) * 4;
        if (c < C) {
            f32x4 x_ = *(const f32x4*)&xr[c];
            if (rr) x_ += *(const f32x4*)&rr[c];
            v[i] = x_;
#pragma unroll
            for (int j = 0; j < 4; ++j) { sum += x_[j]; sq += x_[j] * x_[j]; }
        }
    }
#pragma unroll
    for (int off = 32; off > 0; off >>= 1) {
        sum += __shfl_xor(sum, off, 64);
        sq  += __shfl_xor(sq,  off, 64);
    }
    float mean = sum / (float)C;
    float var  = sq / (float)C - mean * mean;
    float rstd = rsqrtf(var + 1e-5f);
#pragma unroll
    for (int i = 0; i < 2; ++i) {
        int c = (t + i * 64) * 4;
        f32x4 y;
#pragma unroll
        for (int j = 0; j < 4; ++j) y[j] = (v[i][j] - mean) * rstd;
        if (c < C) {
            f32x4 gg = *(const f32x4*)&g[c];
            f32x4 bb = *(const f32x4*)&b[c];
#pragma unroll
            for (int j = 0; j < 4; ++j) y[j] = y[j] * gg[j] + bb[j];
            if (out) *(f32x4*)&out[(size_t)row * C + c] = y;
        }
        if (outb && c < Cpad) {
            u16x4 o;
#pragma unroll
            for (int j = 0; j < 4; ++j) {
                float z = (c + j < C) ? y[j] : 0.f;
                o[j] = f2bf_bits(z);
            }
            *(u16x4*)&outb[(size_t)row * Cpad + c] = o;
        }
    }
}

// ---------------- bf16 MFMA GEMM, 64x64 tile, counted-vmcnt ring pipeline ---
// C = A[M,K] * Bt[N,K]^T + bias. BM=BN=64, BK=64, ring-4 LDS buffers (64 KB),
// 4 waves 2x2, wave tile 32x32. Pre-swizzled global_load_lds; vmcnt(8/4/0).
// QKV mode: weight cols remapped to [Q512 | per-head K32,V32]; phi applied to
// Q and K cols; blocks with bn>=512 additionally compute S_c = V^T K for
// their (chunk, head) pair in the epilogue (replaces attn_state kernel).
template<int RELU, int WF32, int WBF16, int QKV, int K>
__global__ __launch_bounds__(256) void gemm_bf16_kernel(
    const __hip_bfloat16* __restrict__ A, const __hip_bfloat16* __restrict__ Bt,
    const float* __restrict__ bias,
    float* __restrict__ C, __hip_bfloat16* __restrict__ Cb,
    __hip_bfloat16* __restrict__ Sg, float* __restrict__ ksumg,
    int N) {
    constexpr int NSTEP = K / 64;
    __shared__ __align__(16) __hip_bfloat16 As[4][64][64];
    __shared__ __align__(16) __hip_bfloat16 Bs[4][64][64];
    const int tid = threadIdx.x, lane = tid & 63, w = tid >> 6;
    const int nN = N >> 6;
    const int bm = (blockIdx.x / nN) * 64;
    const int bn = (blockIdx.x % nN) * 64;

    const int srow  = lane >> 3;                 // 0..7
    const int sslot = (lane & 7) ^ srow;         // pre-swizzled global slot
    const size_t aoff = (size_t)srow * K + (size_t)sslot * 8;
    const __hip_bfloat16* gA0 = A  + (size_t)(bm + w * 8) * K + aoff;
    const __hip_bfloat16* gA1 = A  + (size_t)(bm + 32 + w * 8) * K + aoff;
    const __hip_bfloat16* gB0 = Bt + (size_t)(bn + w * 8) * K + aoff;
    const __hip_bfloat16* gB1 = Bt + (size_t)(bn + 32 + w * 8) * K + aoff;

#define STAGE(t) do { \
        load_lds16(gA0 + (size_t)(t) * 64, &As[(t) & 3][w * 8][0]); \
        load_lds16(gA1 + (size_t)(t) * 64, &As[(t) & 3][32 + w * 8][0]); \
        load_lds16(gB0 + (size_t)(t) * 64, &Bs[(t) & 3][w * 8][0]); \
        load_lds16(gB1 + (size_t)(t) * 64, &Bs[(t) & 3][32 + w * 8][0]); \
    } while (0)

    const int wm = (w >> 1) << 5, wn = (w & 1) << 5;
    const int fr = lane & 15, fq = lane >> 4;
    const int sw = fr & 7;
    const int e0 = ((fq      ^ sw) << 3);        // k-half 0 slot (swizzled)
    const int e1 = (((fq | 4) ^ sw) << 3);       // k-half 1 slot
    f32x4 acc00 = {0.f, 0.f, 0.f, 0.f}, acc01 = acc00, acc10 = acc00, acc11 = acc00;

    STAGE(0); STAGE(1); STAGE(2);
#pragma unroll
    for (int t = 0; t < NSTEP; ++t) {
        if (NSTEP - t >= 3)      asm volatile("s_waitcnt vmcnt(8)" ::: "memory");
        else if (NSTEP - t == 2) asm volatile("s_waitcnt vmcnt(4)" ::: "memory");
        else                     asm volatile("s_waitcnt vmcnt(0)" ::: "memory");
        __builtin_amdgcn_s_barrier();
        __builtin_amdgcn_sched_barrier(0);
        if (t + 3 < NSTEP) STAGE(t + 3);
        const int b = t & 3;
        bf16x8 a00 = *(const bf16x8*)&As[b][wm + fr][e0];
        bf16x8 a01 = *(const bf16x8*)&As[b][wm + fr][e1];
        bf16x8 a10 = *(const bf16x8*)&As[b][wm + 16 + fr][e0];
        bf16x8 a11 = *(const bf16x8*)&As[b][wm + 16 + fr][e1];
        bf16x8 b00 = *(const bf16x8*)&Bs[b][wn + fr][e0];
        bf16x8 b01 = *(const bf16x8*)&Bs[b][wn + fr][e1];
        bf16x8 b10 = *(const bf16x8*)&Bs[b][wn + 16 + fr][e0];
        bf16x8 b11 = *(const bf16x8*)&Bs[b][wn + 16 + fr][e1];
        acc00 = MFMA_BF16(a00, b00, acc00, 0, 0, 0);
        acc01 = MFMA_BF16(a00, b10, acc01, 0, 0, 0);
        acc10 = MFMA_BF16(a10, b00, acc10, 0, 0, 0);
        acc11 = MFMA_BF16(a10, b10, acc11, 0, 0, 0);
        acc00 = MFMA_BF16(a01, b01, acc00, 0, 0, 0);
        acc01 = MFMA_BF16(a01, b11, acc01, 0, 0, 0);
        acc10 = MFMA_BF16(a11, b01, acc10, 0, 0, 0);
        acc11 = MFMA_BF16(a11, b11, acc11, 0, 0, 0);
    }
#undef STAGE

    const int orow = bm + wm + (fq << 2);
    const int ocol = bn + wn + fr;
    float bv0 = bias[ocol], bv1 = bias[ocol + 16];
    // phi gating: QKV mode -> Q cols (bn<512) and K halves (wn==0) of KV blocks
    const bool dophi = QKV && (bn < 512 || wn == 0);
    const bool kvblk = QKV && (bn >= 512);
    // transposed stash for the attn epilogue (reuses As storage)
    __hip_bfloat16 (*Kt)[72] = reinterpret_cast<__hip_bfloat16 (*)[72]>(&As[0][0][0]);
    __hip_bfloat16 (*Vt)[72] = reinterpret_cast<__hip_bfloat16 (*)[72]>(&As[0][0][0] + 2304);
    if (kvblk) __syncthreads();     // all waves done reading As before reuse

    f32x4 accs[2][2] = {{acc00, acc01}, {acc10, acc11}};
#pragma unroll
    for (int i = 0; i < 2; ++i)
#pragma unroll
        for (int r = 0; r < 4; ++r) {
            int row = orow + i * 16 + r;
            float v0 = accs[i][0][r] + bv0;
            float v1 = accs[i][1][r] + bv1;
            if (RELU) { v0 = fmaxf(v0, 0.f); v1 = fmaxf(v1, 0.f); }
            if (dophi) { v0 = phi(v0); v1 = phi(v1); }
            __hip_bfloat16 b0 = __float2bfloat16(v0);
            __hip_bfloat16 b1 = __float2bfloat16(v1);
            if (WF32) {
                C[(size_t)row * N + ocol]      = v0;
                C[(size_t)row * N + ocol + 16] = v1;
            }
            if (WBF16) {
                Cb[(size_t)row * N + ocol]      = b0;
                Cb[(size_t)row * N + ocol + 16] = b1;
            }
            if (kvblk) {
                int lrow = wm + i * 16 + (fq << 2) + r;
                if (wn == 0) { Kt[fr][lrow] = b0; Kt[16 + fr][lrow] = b1; }
                else         { Vt[fr][lrow] = b0; Vt[16 + fr][lrow] = b1; }
            }
        }

    if (kvblk) {
        __syncthreads();            // Kt/Vt complete
        int b_ = bm >> 10, c_ = (bm >> 6) & 15, hh_ = (bn - 512) >> 6;
        size_t cb = ((size_t)(b_ * NHEAD + hh_) * NCHUNK + c_);
        // S = V^T K, wave quadrant (wr, wc)
        int wr = w >> 1, wc = w & 1;
        f32x4 sacc = {0.f, 0.f, 0.f, 0.f};
#pragma unroll
        for (int ks = 0; ks < 2; ++ks) {
            bf16x8 v_ = *(const bf16x8*)&Vt[wr * 16 + fr][ks * 32 + fq * 8];
            bf16x8 k_ = *(const bf16x8*)&Kt[wc * 16 + fr][ks * 32 + fq * 8];
            sacc = MFMA_BF16(v_, k_, sacc, 0, 0, 0);
        }
        size_t ob = cb * 1024;
#pragma unroll
        for (int r = 0; r < 4; ++r)
            Sg[ob + (size_t)(wr * 16 + (fq << 2) + r) * 32 + wc * 16 + fr] =
                __float2bfloat16(sacc[r]);
        // K column sums (8-lane groups)
        int d = tid >> 3, s0 = (tid & 7) * 8;
        float part = 0.f;
#pragma unroll
        for (int i = 0; i < 8; ++i) part += __bfloat162float(Kt[d][s0 + i]);
        part += __shfl_xor(part, 1, 64);
        part += __shfl_xor(part, 2, 64);
        part += __shfl_xor(part, 4, 64);
        if ((tid & 7) == 0) ksumg[cb * 32 + d] = part;
    }
}

// ---------------- weight transpose + bf16 convert (+ qkv bias concat) -------
// QKV column remap: [Q512 | K_h(32),V_h(32) per head h]
__global__ __launch_bounds__(256) void wconv_kernel(
    const float* __restrict__ W_pre, const float* __restrict__ Wq,
    const float* __restrict__ Wk, const float* __restrict__ Wv,
    const float* __restrict__ Wo, const float* __restrict__ W1,
    const float* __restrict__ W2, const float* __restrict__ W_post,
    const float* __restrict__ bq, const float* __restrict__ bk,
    const float* __restrict__ bv, float* __restrict__ qkvbias,
    __hip_bfloat16* wpre_t, __hip_bfloat16* wqkv_t, __hip_bfloat16* wo_t,
    __hip_bfloat16* w1_t, __hip_bfloat16* w2_t, __hip_bfloat16* wpost_t) {
    __shared__ float tile[64][65];
    int tb = blockIdx.x;
    if (tb >= 2400) {               // qkv bias concat: 6 blocks
        int l = tb - 2400;
        for (int i = threadIdx.x; i < 512; i += 256) {
            qkvbias[l * QKVLD + i] = bq[l * DMODEL + i];
            int kpos = 512 + (i >> 5) * 64 + (i & 31);
            qkvbias[l * QKVLD + kpos]      = bk[l * DMODEL + i];
            qkvbias[l * QKVLD + kpos + 32] = bv[l * DMODEL + i];
        }
        return;
    }
    const float* src; __hip_bfloat16* dst; int K, Kpad, kt, nt, kvmap = 0;
    if (tb < 32) {
        src = W_pre; dst = wpre_t; K = FIN; Kpad = FINPAD;
        kt = tb >> 3; nt = tb & 7;
    } else {
        int t2 = tb - 32; int mat = t2 >> 6; int tt = t2 & 63;
        kt = tt >> 3; nt = tt & 7; K = 512; Kpad = 512;
        if (mat == 36) { src = W_post; dst = wpost_t; }
        else {
            int l = mat / 6, j = mat % 6;
            const size_t WSZ = 262144;
            switch (j) {
                case 0: src = Wq + l * WSZ; dst = wqkv_t + l * 786432;            break;
                case 1: src = Wk + l * WSZ; dst = wqkv_t + l * 786432; kvmap = 1; break;
                case 2: src = Wv + l * WSZ; dst = wqkv_t + l * 786432; kvmap = 2; break;
                case 3: src = Wo + l * WSZ; dst = wo_t + l * WSZ;                 break;
                case 4: src = W1 + l * WSZ; dst = w1_t + l * WSZ;                 break;
                default: src = W2 + l * WSZ; dst = w2_t + l * WSZ;                break;
            }
        }
    }
    const int N = 512;
    int t = threadIdx.x;
    int k0 = kt * 64, n0 = nt * 64;
#pragma unroll
    for (int i = 0; i < 16; ++i) {
        int kk = (t >> 6) * 16 + i;
        int nn = t & 63;
        int k = k0 + kk;
        tile[kk][nn] = (k < K) ? src[(size_t)k * N + n0 + nn] : 0.f;
    }
    __syncthreads();
#pragma unroll
    for (int i = 0; i < 16; ++i) {
        int nn = (t >> 6) * 16 + i;
        int kk = t & 63;
        int n = n0 + nn;
        size_t rr = (size_t)n;
        if (kvmap) rr = 512 + (size_t)(n >> 5) * 64 + ((kvmap == 2) ? 32 : 0) + (n & 31);
        dst[rr * Kpad + k0 + kk] = __float2bfloat16(tile[kk][nn]);
    }
}

// ---------------- attention: intra-chunk (MFMA) + state + output ------------
// grid (NCHUNK, NHEAD, B), 256 threads. qkvb layout: [Q512 | K_h,V_h per head].
__global__ __launch_bounds__(256) void attn_out_kernel(
    const __hip_bfloat16* __restrict__ qkvb,
    const __hip_bfloat16* __restrict__ Sg, const float* __restrict__ ksumg,
    __hip_bfloat16* __restrict__ out) {
    __shared__ __hip_bfloat16 Qs[64][40];
    __shared__ __hip_bfloat16 Ks[64][40];
    __shared__ __hip_bfloat16 Vt[32][72];
    __shared__ __hip_bfloat16 Awb[64][72];
    __shared__ __hip_bfloat16 Stb[32][40];
    __shared__ float den[64];
    __shared__ float ksml[32];
    int c = blockIdx.x, hh = blockIdx.y, b = blockIdx.z;
    int tid = threadIdx.x, lane = tid & 63, w = tid >> 6;
    size_t base = ((size_t)(b * SEQ + c * CHUNK)) * QKVLD;
    size_t rbq  = base + hh * DHEAD;
    size_t rbkv = base + 512 + hh * 64;
    {
        int row = tid >> 2, slot = tid & 3;
        *(bf16x8*)&Qs[row][slot * 8] =
            *(const bf16x8*)&qkvb[rbq + (size_t)row * QKVLD + slot * 8];
        *(bf16x8*)&Ks[row][slot * 8] =
            *(const bf16x8*)&qkvb[rbkv + (size_t)row * QKVLD + slot * 8];
        bf16x8 vv = *(const bf16x8*)&qkvb[rbkv + 32 + (size_t)row * QKVLD + slot * 8];
#pragma unroll
        for (int i = 0; i < 8; ++i)
            Vt[slot * 8 + i][row] = ((const __hip_bfloat16*)&vv)[i];
    }
    // state prefix (sum of prior chunks' S, bf16 chunks, fp32 accumulate)
    size_t sb = ((size_t)((b * NHEAD + hh) * NCHUNK)) * 1024;
    {
        f32x4 st = {0.f, 0.f, 0.f, 0.f};
        for (int cp = 0; cp < c; ++cp) {
            u16x4 sv = *(const u16x4*)&Sg[sb + (size_t)cp * 1024 + tid * 4];
#pragma unroll
            for (int i = 0; i < 4; ++i) st[i] += bf2f(sv[i]);
        }
        int m = tid >> 3, d0 = (tid & 7) * 4;
#pragma unroll
        for (int i = 0; i < 4; ++i) Stb[m][d0 + i] = __float2bfloat16(st[i]);
    }
    if (tid < 32) {
        size_t kb = ((size_t)((b * NHEAD + hh) * NCHUNK)) * 32;
        float s_ = 0.f;
        for (int cp = 0; cp < c; ++cp) s_ += ksumg[kb + cp * 32 + tid];
        ksml[tid] = s_;
    }
    __syncthreads();
    int fr = lane & 15, fq = lane >> 4;
    bf16x8 aQ = *(const bf16x8*)&Qs[w * 16 + fr][fq * 8];
    f32x4 p[4];
#pragma unroll
    for (int j = 0; j < 4; ++j) {
        f32x4 z = {0.f, 0.f, 0.f, 0.f};
        bf16x8 bK = *(const bf16x8*)&Ks[j * 16 + fr][fq * 8];
        p[j] = MFMA_BF16(aQ, bK, z, 0, 0, 0);
    }
    // causal mask + row sums (denominator, fp32)
    float rs[4] = {0.f, 0.f, 0.f, 0.f};
#pragma unroll
    for (int j = 0; j < 4; ++j) {
        int tcol = j * 16 + fr;
#pragma unroll
        for (int r = 0; r < 4; ++r) {
            int s = w * 16 + fq * 4 + r;
            float val = (tcol <= s) ? p[j][r] : 0.f;
            p[j][r] = val;
            rs[r] += val;
        }
    }
#pragma unroll
    for (int off = 8; off > 0; off >>= 1) {
#pragma unroll
        for (int r = 0; r < 4; ++r) rs[r] += __shfl_xor(rs[r], off, 64);
    }
    if (fr == 0) {
#pragma unroll
        for (int r = 0; r < 4; ++r) den[w * 16 + fq * 4 + r] = rs[r];
    }
#pragma unroll
    for (int j = 0; j < 4; ++j)
#pragma unroll
        for (int r = 0; r < 4; ++r)
            Awb[w * 16 + fq * 4 + r][j * 16 + fr] = __float2bfloat16(p[j][r]);
    __syncthreads();
    if (tid < 64) {
        float dq = den[tid];
        float dst_ = 0.f;
#pragma unroll
        for (int d = 0; d < 32; ++d)
            dst_ += __bfloat162float(Qs[tid][d]) * ksml[d];
        den[tid] = 1.f / (dq + dst_ + 1e-6f);
    }
    __syncthreads();
    size_t orb = ((size_t)(b * SEQ + c * CHUNK)) * DMODEL + hh * DHEAD;
#pragma unroll
    for (int mf = 0; mf < 2; ++mf) {
        f32x4 acc = {0.f, 0.f, 0.f, 0.f};
        bf16x8 bS = *(const bf16x8*)&Stb[mf * 16 + fr][fq * 8];
        acc = MFMA_BF16(aQ, bS, acc, 0, 0, 0);
#pragma unroll
        for (int ks = 0; ks < 2; ++ks) {
            bf16x8 aA = *(const bf16x8*)&Awb[w * 16 + fr][ks * 32 + fq * 8];
            bf16x8 bV = *(const bf16x8*)&Vt[mf * 16 + fr][ks * 32 + fq * 8];
            acc = MFMA_BF16(aA, bV, acc, 0, 0, 0);
        }
#pragma unroll
        for (int r = 0; r < 4; ++r) {
            int s = w * 16 + fq * 4 + r;
            out[orb + (size_t)s * DMODEL + mf * 16 + fr] =
                __float2bfloat16(acc[r] * den[s]);
        }
    }
}

// ---------------------------------------------------------------------------
template<int R, int WF, int WB, int QKV, int K>
static inline void gemm(const __hip_bfloat16* A, const __hip_bfloat16* Bt,
                        const float* bias, float* C, __hip_bfloat16* Cb,
                        __hip_bfloat16* Sg, float* ksumg,
                        int M, int N, hipStream_t s) {
    gemm_bf16_kernel<R, WF, WB, QKV, K>
        <<<(M / 64) * (N / 64), 256, 0, s>>>(A, Bt, bias, C, Cb, Sg, ksumg, N);
}

extern "C" void kernel_launch(void* const* d_in, const int* in_sizes, int n_in,
                              void* d_out, int out_size, void* d_ws, size_t ws_size,
                              hipStream_t stream) {
    const float* x      = (const float*)d_in[0];
    const float* g_in   = (const float*)d_in[1];
    const float* b_in   = (const float*)d_in[2];
    const float* W_pre  = (const float*)d_in[3];
    const float* b_pre  = (const float*)d_in[4];
    const float* Wq     = (const float*)d_in[5];
    const float* bq     = (const float*)d_in[6];
    const float* Wk     = (const float*)d_in[7];
    const float* bk     = (const float*)d_in[8];
    const float* Wv     = (const float*)d_in[9];
    const float* bv     = (const float*)d_in[10];
    const float* Wo     = (const float*)d_in[11];
    const float* bo     = (const float*)d_in[12];
    const float* W1     = (const float*)d_in[13];
    const float* bf1    = (const float*)d_in[14];
    const float* W2     = (const float*)d_in[15];
    const float* bf2    = (const float*)d_in[16];
    const float* ln1_g  = (const float*)d_in[17];
    const float* ln1_b  = (const float*)d_in[18];
    const float* ln2_g  = (const float*)d_in[19];
    const float* ln2_b  = (const float*)d_in[20];
    const float* lnf_g  = (const float*)d_in[21];
    const float* lnf_b  = (const float*)d_in[22];
    const float* W_post = (const float*)d_in[23];
    const float* b_post = (const float*)d_in[24];
    (void)in_sizes; (void)n_in; (void)out_size; (void)ws_size;

    float* ws = (float*)d_ws;
    const size_t SZ = (size_t)NROW * DMODEL;          // 1048576
    float* h       = ws;
    float* t1      = h + SZ;
    float* ksumg   = t1 + SZ;                         // 16384
    float* qkvbias = ksumg + 16384;                   // 9216
    __hip_bfloat16* bp = (__hip_bfloat16*)(qkvbias + 9216);
    __hip_bfloat16* Sg     = bp;            bp += 524288;                  // bf16 state chunks
    __hip_bfloat16* hb     = bp;            bp += SZ;
    __hip_bfloat16* qkvb   = bp;            bp += (size_t)NROW * QKVLD;    // 3145728
    __hip_bfloat16* xnb    = bp;            bp += (size_t)NROW * FINPAD;   // 524288
    __hip_bfloat16* attb   = bp;            bp += SZ;
    __hip_bfloat16* ffb    = bp;            bp += SZ;
    __hip_bfloat16* t0b    = bp;            bp += SZ;
    __hip_bfloat16* wpre_t = bp;            bp += (size_t)DMODEL * FINPAD; // 131072
    __hip_bfloat16* wqkv_t = bp;            bp += (size_t)NLAYER * 786432;
    __hip_bfloat16* wo_t   = bp;            bp += (size_t)NLAYER * 262144;
    __hip_bfloat16* w1_t   = bp;            bp += (size_t)NLAYER * 262144;
    __hip_bfloat16* w2_t   = bp;            bp += (size_t)NLAYER * 262144;
    __hip_bfloat16* wpost_t= bp;

    // one-time-per-call weight conversion + qkv bias concat (remapped layout)
    wconv_kernel<<<2406, 256, 0, stream>>>(
        W_pre, Wq, Wk, Wv, Wo, W1, W2, W_post,
        bq, bk, bv, qkvbias,
        wpre_t, wqkv_t, wo_t, w1_t, w2_t, wpost_t);

    // input LN (bf16, K padded 240->256) + pre projection (h fp32 + hb bf16)
    ln_kernel<<<NROW, 64, 0, stream>>>(x, nullptr, g_in, b_in, nullptr, xnb, FIN, FINPAD);
    gemm<0, 1, 1, 0, FINPAD>(xnb, wpre_t, b_pre, h, hb, nullptr, nullptr,
                             NROW, DMODEL, stream);

    dim3 ag(NCHUNK, NHEAD, 2);
    for (int l = 0; l < NLAYER; ++l) {
        // fused QKV projection -> bf16 qkvb + per-chunk V^T K state (Sg, ksumg)
        gemm<0, 0, 1, 1, DMODEL>(hb, wqkv_t + (size_t)l * 786432, qkvbias + l * QKVLD,
                                 nullptr, qkvb, Sg, ksumg, NROW, QKVLD, stream);
        attn_out_kernel<<<ag, 256, 0, stream>>>(qkvb, Sg, ksumg, attb);
        gemm<0, 1, 0, 0, DMODEL>(attb, wo_t + (size_t)l * 262144, bo + l * DMODEL,
                                 t1, nullptr, nullptr, nullptr, NROW, DMODEL, stream);
        ln_kernel<<<NROW, 64, 0, stream>>>(h, t1, ln1_g + l * DMODEL, ln1_b + l * DMODEL,
                                           h, hb, DMODEL, DMODEL);
        gemm<1, 0, 1, 0, DMODEL>(hb, w1_t + (size_t)l * 262144, bf1 + l * DMODEL,
                                 nullptr, ffb, nullptr, nullptr, NROW, DMODEL, stream);
        gemm<0, 1, 0, 0, DMODEL>(ffb, w2_t + (size_t)l * 262144, bf2 + l * DMODEL,
                                 t1, nullptr, nullptr, nullptr, NROW, DMODEL, stream);
        ln_kernel<<<NROW, 64, 0, stream>>>(h, t1, ln2_g + l * DMODEL, ln2_b + l * DMODEL,
                                           h, hb, DMODEL, DMODEL);
    }

    // final LN (bf16 only) + post projection (fp32 to d_out)
    ln_kernel<<<NROW, 64, 0, stream>>>(h, nullptr, lnf_g, lnf_b, nullptr, t0b, DMODEL, DMODEL);
    gemm<0, 1, 0, 0, DMODEL>(t0b, wpost_t, b_post, (float*)d_out, nullptr,
                             nullptr, nullptr, NROW, DMODEL, stream);
}